// Round 9
// baseline (1326.430 us; speedup 1.0000x reference)
//
#include <hip/hip_runtime.h>

#define NB 8
#define TT 24
#define NN 4000
#define FF 32
#define HH 128
#define EE 64000

typedef float f32x4 __attribute__((ext_vector_type(4)));
typedef short bf16x8 __attribute__((ext_vector_type(8)));
#define MFMA16(a, b, c) __builtin_amdgcn_mfma_f32_16x16x32_bf16(a, b, c, 0, 0, 0)

// fast gate math: v_exp + v_rcp (rel err ~1e-7, negligible vs bf16-split error)
__device__ __forceinline__ float fsig(float x) {
  return __builtin_amdgcn_rcpf(1.0f + __expf(-x));
}
__device__ __forceinline__ float ftanh(float x) {
  return 1.0f - 2.0f * __builtin_amdgcn_rcpf(__expf(2.0f * x) + 1.0f);
}

// round-to-nearest-even fp32 -> bf16; returns bits, sets *hif to the bf16 value as fp32
__device__ __forceinline__ unsigned short rne16(float x, float* hif) {
  unsigned u = __float_as_uint(x);
  unsigned r = (u + 0x7FFFu + ((u >> 16) & 1u)) >> 16;
  *hif = __uint_as_float(r << 16);
  return (unsigned short)r;
}

// RNE-rounded bf16 in the TOP 16 bits (for perm-based pair packing)
__device__ __forceinline__ unsigned rnd_top(float x) {
  unsigned u = __float_as_uint(x);
  return u + 0x7FFFu + ((u >> 16) & 1u);
}

// ---------- setup: pack weights into MFMA fragment order (hi/lo split), combine bias, init deg ----------
__global__ void setup_kernel(const float* __restrict__ W_ih, const float* __restrict__ W_hh,
                             const float* __restrict__ b_ih, const float* __restrict__ b_hh,
                             const float* __restrict__ gcn_W,
                             unsigned short* __restrict__ Wbh_hi, unsigned short* __restrict__ Wbh_lo,
                             unsigned short* __restrict__ Wbi_hi, unsigned short* __restrict__ Wbi_lo,
                             float* __restrict__ gcn_WT, float* __restrict__ bias,
                             float* __restrict__ deg) {
  int idx = blockIdx.x * 256 + threadIdx.x;
  if (idx < 65536) {
    int e = idx & 7, l = (idx >> 3) & 63, ks = (idx >> 9) & 3, nt = idx >> 11;
    int gate = nt * 16 + (l & 15);
    int k = ks * 32 + (l >> 4) * 8 + e;
    float wv = W_hh[gate * 128 + k];
    float hif, d;
    unsigned short hb = rne16(wv, &hif);
    unsigned short lb = rne16(wv - hif, &d);
    Wbh_hi[idx] = hb;
    Wbh_lo[idx] = lb;
  } else if (idx < 65536 + 16384) {
    int p = idx - 65536;
    int e = p & 7, l = (p >> 3) & 63, nt = p >> 9;
    int gate = nt * 16 + (l & 15);
    int k = (l >> 4) * 8 + e;
    float wv = W_ih[gate * 32 + k];
    float hif, d;
    unsigned short hb = rne16(wv, &hif);
    unsigned short lb = rne16(wv - hif, &d);
    Wbi_hi[p] = hb;
    Wbi_lo[p] = lb;
  } else if (idx < 65536 + 16384 + 16384) {
    int p = idx - 65536 - 16384;
    int g = p & 127, k = p >> 7;
    gcn_WT[p] = gcn_W[g * 128 + k];
  } else if (idx < 65536 + 16384 + 16384 + 512) {
    int g = idx - (65536 + 16384 + 16384);
    bias[g] = b_ih[g] + b_hh[g];
  } else if (idx < 65536 + 16384 + 16384 + 512 + NN) {
    int n = idx - (65536 + 16384 + 16384 + 512);
    deg[n] = 1.0f;  // self-loop
  }
}

// ---------- x pre-split: B-fragment-ready bf16 hi/lo ----------
__global__ __launch_bounds__(256) void xsplit_kernel(const float* __restrict__ x,
                                                     unsigned short* __restrict__ xpk) {
  int gid = blockIdx.x * 256 + threadIdx.x;  // exactly 2000*24*64
  int l = gid & 63;
  int t = (gid >> 6) % TT;
  int rt = gid / (TT * 64);
  int col = l & 15, kc = l >> 4;
  int r = rt * 16 + col;              // NN%16==0 -> tile never straddles batch
  int b = (rt * 16) / NN;
  int n = r - b * NN;
  const float* src = x + (((size_t)b * TT + t) * NN + n) * FF + kc * 8;
  float4 p0 = *(const float4*)src;
  float4 p1 = *(const float4*)(src + 4);
  float xf[8] = {p0.x, p0.y, p0.z, p0.w, p1.x, p1.y, p1.z, p1.w};
  bf16x8 vh, vl;
#pragma unroll
  for (int e = 0; e < 8; ++e) {
    float hif, d;
    vh[e] = (short)rne16(xf[e], &hif);
    vl[e] = (short)rne16(xf[e] - hif, &d);
  }
  size_t ob = (size_t)(rt * TT + t) * 1024 + l * 8;
  *(bf16x8*)(xpk + ob) = vh;
  *(bf16x8*)(xpk + ob + 512) = vl;
}

// ---------- LSTM via split-bf16 MFMA, anti-phase groups ----------
// 8 waves, 64 seqs/block = 2 independent groups of 32 seqs (waves 0-3 = A, 4-7 = B).
// Group B runs one barrier-interval behind A; SIMD s hosts waves s (A) and s+4 (B),
// so every interval pairs {one wave's MFMA phase} || {the other's gate epilogue}.
// __launch_bounds__(512,2): 2 waves/SIMD -> 256-VGPR class; ~190 live regs, NO spill.
__global__ __launch_bounds__(512, 2) void lstm_kernel(
    const unsigned short* __restrict__ xpk,  // pre-split x fragments
    const unsigned short* __restrict__ Wbh_hi, const unsigned short* __restrict__ Wbh_lo,
    const unsigned short* __restrict__ Wbi_hi, const unsigned short* __restrict__ Wbi_lo,
    const float* __restrict__ bias,          // [512] combined
    float* __restrict__ h_out)               // [B*N, H] fp32
{
  __shared__ unsigned short hbuf[2][2][32 * 128];  // [grp][hi/lo][row*128+j] : 32 KB
  const int tid = threadIdx.x;
  const int w = tid >> 6, l = tid & 63;
  const int grp = w >> 2, w4 = w & 3;
  const int col = l & 15, kc = l >> 4;
  const int blk = blockIdx.x;

  // zero both groups' h(0)
  {
    uint4* p0 = (uint4*)&hbuf[0][0][0];
    for (int i = tid; i < 2048; i += 512) p0[i] = make_uint4(0, 0, 0, 0);
  }

  const char* hb_hi = (const char*)&hbuf[grp][0][0];
  const char* hb_lo = (const char*)&hbuf[grp][1][0];
  char* hw_hi = (char*)&hbuf[grp][0][0];
  char* hw_lo = (char*)&hbuf[grp][1][0];

  // bias fragments: bqq[q] = bias[(4q+w4)*16 + 4kc ..+4) (C-operand seed at ks==0)
  f32x4 bqq[8];
#pragma unroll
  for (int q = 0; q < 8; ++q) bqq[q] = *(const f32x4*)(bias + (4 * q + w4) * 16 + 4 * kc);

  float c[2][2][4];  // [sq][u][r]
#pragma unroll
  for (int sq = 0; sq < 2; ++sq)
#pragma unroll
    for (int u = 0; u < 2; ++u)
#pragma unroll
      for (int r = 0; r < 4; ++r) c[sq][u][r] = 0.0f;

  f32x4 acc[2][8];  // [sq][q]
  const int rtA = blk * 4 + grp * 2;  // global 16-row tile base for this group

  auto mfma_phase = [&](int t) {
    // x fragments (pre-split) — issue first, consumed last
    bf16x8 xh[2], xl[2];
#pragma unroll
    for (int sq = 0; sq < 2; ++sq) {
      const unsigned short* xb = xpk + ((size_t)(rtA + sq) * TT + t) * 1024 + l * 8;
      xh[sq] = *(const bf16x8*)xb;
      xl[sq] = *(const bf16x8*)(xb + 512);
    }
    __builtin_amdgcn_s_setprio(1);
    // recurrence: W_hh(A) x h(B), split-bf16
#pragma unroll
    for (int ks = 0; ks < 4; ++ks) {
      bf16x8 bh[2], bl_[2];
#pragma unroll
      for (int sq = 0; sq < 2; ++sq) {
        int off = (16 * sq + col) * 256 + (((4 * ks + kc) ^ col) << 4);
        bh[sq] = *(const bf16x8*)(hb_hi + off);
        bl_[sq] = *(const bf16x8*)(hb_lo + off);
      }
#pragma unroll
      for (int q = 0; q < 8; ++q) {
        size_t wo = ((size_t)((4 * q + w4) * 4 + ks) * 64 + l) * 8;
        bf16x8 wh = *(const bf16x8*)(Wbh_hi + wo);
        bf16x8 wl = *(const bf16x8*)(Wbh_lo + wo);
#pragma unroll
        for (int sq = 0; sq < 2; ++sq) {
          acc[sq][q] = MFMA16(wh, bh[sq], ks == 0 ? bqq[q] : acc[sq][q]);
          acc[sq][q] = MFMA16(wh, bl_[sq], acc[sq][q]);
          acc[sq][q] = MFMA16(wl, bh[sq], acc[sq][q]);
        }
      }
    }
    // input projection: W_ih(A) x x(B)
#pragma unroll
    for (int q = 0; q < 8; ++q) {
      size_t wo = ((size_t)(4 * q + w4) * 64 + l) * 8;
      bf16x8 wh = *(const bf16x8*)(Wbi_hi + wo);
      bf16x8 wl = *(const bf16x8*)(Wbi_lo + wo);
#pragma unroll
      for (int sq = 0; sq < 2; ++sq) {
        acc[sq][q] = MFMA16(wh, xh[sq], acc[sq][q]);
        acc[sq][q] = MFMA16(wh, xl[sq], acc[sq][q]);
        acc[sq][q] = MFMA16(wl, xh[sq], acc[sq][q]);
      }
    }
    __builtin_amdgcn_s_setprio(0);
  };

  auto epi_phase = [&](int t) {
    // q = 2g+u : gate g of j-block jb = w4 + 4u
#pragma unroll
    for (int sq = 0; sq < 2; ++sq) {
#pragma unroll
      for (int u = 0; u < 2; ++u) {
        int jb = w4 + 4 * u;
        unsigned uh[4], ul[4];
        float hv[4];
#pragma unroll
        for (int r = 0; r < 4; ++r) {
          float iv = fsig(acc[sq][0 + u][r]);
          float fv = fsig(acc[sq][2 + u][r]);
          float gv = ftanh(acc[sq][4 + u][r]);
          float ov = fsig(acc[sq][6 + u][r]);
          float cc = fv * c[sq][u][r] + iv * gv;
          c[sq][u][r] = cc;
          float hh = ov * ftanh(cc);
          hv[r] = hh;
          unsigned uu = __float_as_uint(hh);
          uh[r] = uu;  // hi = trunc bf16 (bytes 2,3)
          float hif = __uint_as_float(uu & 0xFFFF0000u);
          ul[r] = rnd_top(hh - hif);  // lo = RNE bf16 in top bits
        }
        // pack pairs via byte-perm: dst = [lo16(p0), hi16<-p1]
        uint2 phi, plo;
        phi.x = __builtin_amdgcn_perm(uh[1], uh[0], 0x07060302u);
        phi.y = __builtin_amdgcn_perm(uh[3], uh[2], 0x07060302u);
        plo.x = __builtin_amdgcn_perm(ul[1], ul[0], 0x07060302u);
        plo.y = __builtin_amdgcn_perm(ul[3], ul[2], 0x07060302u);
        int row = 16 * sq + col;
        int cs = (2 * jb + (kc >> 1)) ^ col;
        int woff = row * 256 + cs * 16 + 8 * (kc & 1);
        *(uint2*)(hw_hi + woff) = phi;
        *(uint2*)(hw_lo + woff) = plo;
        if (t == TT - 1) {
          int rowg = blk * 64 + grp * 32 + 16 * sq + col;
          *(float4*)&h_out[(size_t)rowg * HH + 16 * jb + 4 * kc] =
              make_float4(hv[0], hv[1], hv[2], hv[3]);
        }
      }
    }
  };

  __syncthreads();              // h(0) visible
  if (grp) __syncthreads();     // offset group B by one interval
  for (int t = 0; t < TT; ++t) {
    mfma_phase(t);
    __syncthreads();
    epi_phase(t);
    __syncthreads();
  }
  if (!grp) __syncthreads();    // rebalance barrier count
}

// ---------- GCN ----------
__global__ void deg_kernel(const int* __restrict__ ei, float* __restrict__ deg) {
  int e = blockIdx.x * 256 + threadIdx.x;
  if (e < EE) atomicAdd(&deg[ei[EE + e]], 1.0f);  // dst row
}

__global__ void dinv_kernel(const float* __restrict__ deg, float* __restrict__ dinv) {
  int n = blockIdx.x * 256 + threadIdx.x;
  if (n < NN) dinv[n] = 1.0f / sqrtf(deg[n]);  // deg >= 1 (self loop)
}

// xw[b,n,g] = sum_k h[b,n,k] * gcn_W[g,k]  ; 8 rows per block
__global__ __launch_bounds__(128) void xw_kernel(const float* __restrict__ h,
                                                 const float* __restrict__ gcn_WT,
                                                 float* __restrict__ xw) {
  const int r0 = blockIdx.x * 8;
  const int g = threadIdx.x;
  __shared__ float hs[8][HH];
  for (int m = 0; m < 8; ++m) hs[m][g] = h[(size_t)(r0 + m) * HH + g];
  __syncthreads();
  float acc[8] = {0, 0, 0, 0, 0, 0, 0, 0};
#pragma unroll 4
  for (int k = 0; k < HH; ++k) {
    float w = gcn_WT[k * HH + g];
#pragma unroll
    for (int m = 0; m < 8; ++m) acc[m] += hs[m][k] * w;
  }
  for (int m = 0; m < 8; ++m) xw[(size_t)(r0 + m) * HH + g] = acc[m];
}

// scatter: agg[b,dst,:] += xw[b,src,:] * norm(e); thread = (edge, channel)
__global__ void scatter_kernel(const int* __restrict__ ei, const float* __restrict__ xw,
                               const float* __restrict__ dinv, float* __restrict__ agg) {
  int gid = blockIdx.x * 256 + threadIdx.x;
  int e = gid >> 7;
  int jj = gid & 127;
  if (e >= EE) return;
  int s = ei[e];
  int d = ei[EE + e];
  float nrm = dinv[s] * dinv[d];
#pragma unroll
  for (int b = 0; b < NB; ++b) {
    float v = xw[((size_t)b * NN + s) * HH + jj] * nrm;
    atomicAdd(&agg[((size_t)b * NN + d) * HH + jj], v);
  }
}

// final: add self-loop + bias, relu, two dot heads. one wave per row.
__global__ __launch_bounds__(256) void final_kernel(
    const float* __restrict__ agg, const float* __restrict__ xw, const float* __restrict__ dinv,
    const float* __restrict__ gcn_b, const float* __restrict__ fcw_c, const float* __restrict__ fcb_c,
    const float* __restrict__ fcw_i, const float* __restrict__ fcb_i, float* __restrict__ out) {
  int row = blockIdx.x * 4 + (threadIdx.x >> 6);
  int lane = threadIdx.x & 63;
  int n = row % NN;
  float sn = dinv[n] * dinv[n];
  float sc = 0.0f, si = 0.0f;
  for (int jj = lane; jj < HH; jj += 64) {
    float v = agg[(size_t)row * HH + jj] + xw[(size_t)row * HH + jj] * sn + gcn_b[jj];
    v = fmaxf(v, 0.0f);
    sc += v * fcw_c[jj];
    si += v * fcw_i[jj];
  }
#pragma unroll
  for (int off = 32; off > 0; off >>= 1) {
    sc += __shfl_down(sc, off);
    si += __shfl_down(si, off);
  }
  if (lane == 0) {
    out[row] = sc + fcb_c[0];
    out[NB * NN + row] = si + fcb_i[0];
  }
}

extern "C" void kernel_launch(void* const* d_in, const int* in_sizes, int n_in,
                              void* d_out, int out_size, void* d_ws, size_t ws_size,
                              hipStream_t stream) {
  const float* x     = (const float*)d_in[0];
  const int*   ei    = (const int*)d_in[1];
  const float* W_ih  = (const float*)d_in[2];
  const float* W_hh  = (const float*)d_in[3];
  const float* b_ih  = (const float*)d_in[4];
  const float* b_hh  = (const float*)d_in[5];
  const float* gcn_W = (const float*)d_in[6];
  const float* gcn_b = (const float*)d_in[7];
  const float* fcw_c = (const float*)d_in[8];
  const float* fcb_c = (const float*)d_in[9];
  const float* fcw_i = (const float*)d_in[10];
  const float* fcb_i = (const float*)d_in[11];
  float* out = (float*)d_out;

  char* cur = (char*)d_ws;
  unsigned short* Wbh_hi = (unsigned short*)cur; cur += 65536 * 2;
  unsigned short* Wbh_lo = (unsigned short*)cur; cur += 65536 * 2;
  unsigned short* Wbi_hi = (unsigned short*)cur; cur += 16384 * 2;
  unsigned short* Wbi_lo = (unsigned short*)cur; cur += 16384 * 2;
  float* gcn_WT = (float*)cur; cur += 16384 * 4;
  float* bias   = (float*)cur; cur += 512 * 4;
  float* deg    = (float*)cur; cur += 4000 * 4;
  float* dinv   = (float*)cur; cur += 4000 * 4;
  float* h_all  = (float*)cur; cur += (size_t)4096000 * 4;
  // overlay region: xpk (98.3 MB, live only during lstm) | xw+agg (live after lstm)
  unsigned short* xpk = (unsigned short*)cur;           // 2000*24*2*512 ushorts
  float* xw  = (float*)cur;                              // 4,096,000 floats
  float* agg = xw + 4096000;                             // 4,096,000 floats

  setup_kernel<<<402, 256, 0, stream>>>(W_ih, W_hh, b_ih, b_hh, gcn_W,
                                        Wbh_hi, Wbh_lo, Wbi_hi, Wbi_lo,
                                        gcn_WT, bias, deg);
  xsplit_kernel<<<(2000 * TT * 64) / 256, 256, 0, stream>>>(x, xpk);
  lstm_kernel<<<(NB * NN) / 64, 512, 0, stream>>>(xpk, Wbh_hi, Wbh_lo, Wbi_hi, Wbi_lo,
                                                  bias, h_all);
  // xpk dead from here; agg/xw reuse its space
  hipMemsetAsync(agg, 0, (size_t)4096000 * sizeof(float), stream);
  deg_kernel<<<EE / 256, 256, 0, stream>>>(ei, deg);
  dinv_kernel<<<(NN + 255) / 256, 256, 0, stream>>>(deg, dinv);
  xw_kernel<<<(NB * NN) / 8, 128, 0, stream>>>(h_all, gcn_WT, xw);
  scatter_kernel<<<(EE * 128) / 256, 256, 0, stream>>>(ei, xw, dinv, agg);
  final_kernel<<<(NB * NN) / 4, 256, 0, stream>>>(agg, xw, dinv, gcn_b, fcw_c, fcb_c,
                                                  fcw_i, fcb_i, out);
}

// Round 10
// 1325.588 us; speedup vs baseline: 1.0006x; 1.0006x over previous
//
#include <hip/hip_runtime.h>

#define NB 8
#define TT 24
#define NN 4000
#define FF 32
#define HH 128
#define EE 64000

typedef float f32x4 __attribute__((ext_vector_type(4)));
typedef short bf16x8 __attribute__((ext_vector_type(8)));
#define MFMA16(a, b, c) __builtin_amdgcn_mfma_f32_16x16x32_bf16(a, b, c, 0, 0, 0)

// fast gate math: v_exp + v_rcp (rel err ~1e-7, negligible vs bf16-split error)
__device__ __forceinline__ float fsig(float x) {
  return __builtin_amdgcn_rcpf(1.0f + __expf(-x));
}
__device__ __forceinline__ float ftanh(float x) {
  return 1.0f - 2.0f * __builtin_amdgcn_rcpf(__expf(2.0f * x) + 1.0f);
}

// round-to-nearest-even fp32 -> bf16; returns bits, sets *hif to the bf16 value as fp32
__device__ __forceinline__ unsigned short rne16(float x, float* hif) {
  unsigned u = __float_as_uint(x);
  unsigned r = (u + 0x7FFFu + ((u >> 16) & 1u)) >> 16;
  *hif = __uint_as_float(r << 16);
  return (unsigned short)r;
}

// RNE-rounded bf16 in the TOP 16 bits (for perm-based pair packing)
__device__ __forceinline__ unsigned rnd_top(float x) {
  unsigned u = __float_as_uint(x);
  return u + 0x7FFFu + ((u >> 16) & 1u);
}

// ---------- setup: pack weights into MFMA fragment order (hi/lo split), combine bias, init deg ----------
__global__ void setup_kernel(const float* __restrict__ W_ih, const float* __restrict__ W_hh,
                             const float* __restrict__ b_ih, const float* __restrict__ b_hh,
                             const float* __restrict__ gcn_W,
                             unsigned short* __restrict__ Wbh_hi, unsigned short* __restrict__ Wbh_lo,
                             unsigned short* __restrict__ Wbi_hi, unsigned short* __restrict__ Wbi_lo,
                             float* __restrict__ gcn_WT, float* __restrict__ bias,
                             float* __restrict__ deg) {
  int idx = blockIdx.x * 256 + threadIdx.x;
  if (idx < 65536) {
    int e = idx & 7, l = (idx >> 3) & 63, ks = (idx >> 9) & 3, nt = idx >> 11;
    int gate = nt * 16 + (l & 15);
    int k = ks * 32 + (l >> 4) * 8 + e;
    float wv = W_hh[gate * 128 + k];
    float hif, d;
    unsigned short hb = rne16(wv, &hif);
    unsigned short lb = rne16(wv - hif, &d);
    Wbh_hi[idx] = hb;
    Wbh_lo[idx] = lb;
  } else if (idx < 65536 + 16384) {
    int p = idx - 65536;
    int e = p & 7, l = (p >> 3) & 63, nt = p >> 9;
    int gate = nt * 16 + (l & 15);
    int k = (l >> 4) * 8 + e;
    float wv = W_ih[gate * 32 + k];
    float hif, d;
    unsigned short hb = rne16(wv, &hif);
    unsigned short lb = rne16(wv - hif, &d);
    Wbi_hi[p] = hb;
    Wbi_lo[p] = lb;
  } else if (idx < 65536 + 16384 + 16384) {
    int p = idx - 65536 - 16384;
    int g = p & 127, k = p >> 7;
    gcn_WT[p] = gcn_W[g * 128 + k];
  } else if (idx < 65536 + 16384 + 16384 + 512) {
    int g = idx - (65536 + 16384 + 16384);
    bias[g] = b_ih[g] + b_hh[g];
  } else if (idx < 65536 + 16384 + 16384 + 512 + NN) {
    int n = idx - (65536 + 16384 + 16384 + 512);
    deg[n] = 1.0f;  // self-loop
  }
}

// ---------- x pre-split: B-fragment-ready bf16 hi/lo ----------
__global__ __launch_bounds__(256) void xsplit_kernel(const float* __restrict__ x,
                                                     unsigned short* __restrict__ xpk) {
  int gid = blockIdx.x * 256 + threadIdx.x;  // exactly 2000*24*64
  int l = gid & 63;
  int t = (gid >> 6) % TT;
  int rt = gid / (TT * 64);
  int col = l & 15, kc = l >> 4;
  int r = rt * 16 + col;              // NN%16==0 -> tile never straddles batch
  int b = (rt * 16) / NN;
  int n = r - b * NN;
  const float* src = x + (((size_t)b * TT + t) * NN + n) * FF + kc * 8;
  float4 p0 = *(const float4*)src;
  float4 p1 = *(const float4*)(src + 4);
  float xf[8] = {p0.x, p0.y, p0.z, p0.w, p1.x, p1.y, p1.z, p1.w};
  bf16x8 vh, vl;
#pragma unroll
  for (int e = 0; e < 8; ++e) {
    float hif, d;
    vh[e] = (short)rne16(xf[e], &hif);
    vl[e] = (short)rne16(xf[e] - hif, &d);
  }
  size_t ob = (size_t)(rt * TT + t) * 1024 + l * 8;
  *(bf16x8*)(xpk + ob) = vh;
  *(bf16x8*)(xpk + ob + 512) = vl;
}

// ---------- LSTM via split-bf16 MFMA, anti-phase groups (straight-line, no lambdas) ----------
// 8 waves, 64 seqs/block = 2 groups of 32 seqs (waves 0-3 = A, 4-7 = B). Group B runs one
// barrier-interval behind A; SIMD s hosts waves s (A) and s+4 (B), so every interval pairs
// {one wave's MFMA phase} || {the other's gate epilogue}. acc lives INSIDE the t-loop
// (straight-line code, static indices) so SROA keeps it in registers — no scratch.
__global__ __launch_bounds__(512, 2) void lstm_kernel(
    const unsigned short* __restrict__ xpk,  // pre-split x fragments
    const unsigned short* __restrict__ Wbh_hi, const unsigned short* __restrict__ Wbh_lo,
    const unsigned short* __restrict__ Wbi_hi, const unsigned short* __restrict__ Wbi_lo,
    const float* __restrict__ bias,          // [512] combined
    float* __restrict__ h_out)               // [B*N, H] fp32
{
  __shared__ unsigned short hbuf[2][2][32 * 128];  // [grp][hi/lo][row*128+j] : 32 KB
  const int tid = threadIdx.x;
  const int w = tid >> 6, l = tid & 63;
  const int grp = w >> 2, w4 = w & 3;
  const int col = l & 15, kc = l >> 4;
  const int blk = blockIdx.x;

  // zero both groups' h(0)
  {
    uint4* p0 = (uint4*)&hbuf[0][0][0];
    for (int i = tid; i < 2048; i += 512) p0[i] = make_uint4(0, 0, 0, 0);
  }

  const char* hb_hi = (const char*)&hbuf[grp][0][0];
  const char* hb_lo = (const char*)&hbuf[grp][1][0];
  char* hw_hi = (char*)&hbuf[grp][0][0];
  char* hw_lo = (char*)&hbuf[grp][1][0];

  // bias fragments: bqq[q] = bias[(4q+w4)*16 + 4kc ..+4) (C-operand seed at ks==0)
  f32x4 bqq[8];
#pragma unroll
  for (int q = 0; q < 8; ++q) bqq[q] = *(const f32x4*)(bias + (4 * q + w4) * 16 + 4 * kc);

  float c[2][2][4];  // [sq][u][r]
#pragma unroll
  for (int sq = 0; sq < 2; ++sq)
#pragma unroll
    for (int u = 0; u < 2; ++u)
#pragma unroll
      for (int r = 0; r < 4; ++r) c[sq][u][r] = 0.0f;

  const int rtA = blk * 4 + grp * 2;  // global 16-row tile base for this group

  __syncthreads();              // h(0) visible
  if (grp) __syncthreads();     // offset group B by one interval (counting barrier pairing)

  for (int t = 0; t < TT; ++t) {
    // ================= MFMA phase =================
    // x fragments (pre-split) — issue first, consumed last
    bf16x8 xh[2], xl[2];
#pragma unroll
    for (int sq = 0; sq < 2; ++sq) {
      const unsigned short* xb = xpk + ((size_t)(rtA + sq) * TT + t) * 1024 + l * 8;
      xh[sq] = *(const bf16x8*)xb;
      xl[sq] = *(const bf16x8*)(xb + 512);
    }

    f32x4 acc[2][8];  // [sq][q] — inside loop body, static indices only
    __builtin_amdgcn_s_setprio(1);
    // recurrence: W_hh(A) x h(B), split-bf16
#pragma unroll
    for (int ks = 0; ks < 4; ++ks) {
      bf16x8 bh[2], bl_[2];
#pragma unroll
      for (int sq = 0; sq < 2; ++sq) {
        int off = (16 * sq + col) * 256 + (((4 * ks + kc) ^ col) << 4);
        bh[sq] = *(const bf16x8*)(hb_hi + off);
        bl_[sq] = *(const bf16x8*)(hb_lo + off);
      }
#pragma unroll
      for (int q = 0; q < 8; ++q) {
        size_t wo = ((size_t)((4 * q + w4) * 4 + ks) * 64 + l) * 8;
        bf16x8 wh = *(const bf16x8*)(Wbh_hi + wo);
        bf16x8 wl = *(const bf16x8*)(Wbh_lo + wo);
#pragma unroll
        for (int sq = 0; sq < 2; ++sq) {
          acc[sq][q] = MFMA16(wh, bh[sq], ks == 0 ? bqq[q] : acc[sq][q]);
          acc[sq][q] = MFMA16(wh, bl_[sq], acc[sq][q]);
          acc[sq][q] = MFMA16(wl, bh[sq], acc[sq][q]);
        }
      }
    }
    // input projection: W_ih(A) x x(B)
#pragma unroll
    for (int q = 0; q < 8; ++q) {
      size_t wo = ((size_t)(4 * q + w4) * 64 + l) * 8;
      bf16x8 wh = *(const bf16x8*)(Wbi_hi + wo);
      bf16x8 wl = *(const bf16x8*)(Wbi_lo + wo);
#pragma unroll
      for (int sq = 0; sq < 2; ++sq) {
        acc[sq][q] = MFMA16(wh, xh[sq], acc[sq][q]);
        acc[sq][q] = MFMA16(wh, xl[sq], acc[sq][q]);
        acc[sq][q] = MFMA16(wl, xh[sq], acc[sq][q]);
      }
    }
    __builtin_amdgcn_s_setprio(0);

    __syncthreads();

    // ================= epilogue phase =================
    // q = 2g+u : gate g of j-block jb = w4 + 4u
#pragma unroll
    for (int sq = 0; sq < 2; ++sq) {
#pragma unroll
      for (int u = 0; u < 2; ++u) {
        int jb = w4 + 4 * u;
        unsigned uh[4], ul[4];
        float hv[4];
#pragma unroll
        for (int r = 0; r < 4; ++r) {
          float iv = fsig(acc[sq][0 + u][r]);
          float fv = fsig(acc[sq][2 + u][r]);
          float gv = ftanh(acc[sq][4 + u][r]);
          float ov = fsig(acc[sq][6 + u][r]);
          float cc = fv * c[sq][u][r] + iv * gv;
          c[sq][u][r] = cc;
          float hh = ov * ftanh(cc);
          hv[r] = hh;
          unsigned uu = __float_as_uint(hh);
          uh[r] = uu;  // hi = trunc bf16 (bytes 2,3)
          float hif = __uint_as_float(uu & 0xFFFF0000u);
          ul[r] = rnd_top(hh - hif);  // lo = RNE bf16 in top bits
        }
        // pack pairs via byte-perm: dst = [lo16(p0), hi16<-p1]
        uint2 phi, plo;
        phi.x = __builtin_amdgcn_perm(uh[1], uh[0], 0x07060302u);
        phi.y = __builtin_amdgcn_perm(uh[3], uh[2], 0x07060302u);
        plo.x = __builtin_amdgcn_perm(ul[1], ul[0], 0x07060302u);
        plo.y = __builtin_amdgcn_perm(ul[3], ul[2], 0x07060302u);
        int row = 16 * sq + col;
        int cs = (2 * jb + (kc >> 1)) ^ col;
        int woff = row * 256 + cs * 16 + 8 * (kc & 1);
        *(uint2*)(hw_hi + woff) = phi;
        *(uint2*)(hw_lo + woff) = plo;
        if (t == TT - 1) {
          int rowg = blk * 64 + grp * 32 + 16 * sq + col;
          *(float4*)&h_out[(size_t)rowg * HH + 16 * jb + 4 * kc] =
              make_float4(hv[0], hv[1], hv[2], hv[3]);
        }
      }
    }
    __syncthreads();
  }
  if (!grp) __syncthreads();    // rebalance barrier count
}

// ---------- GCN ----------
__global__ void deg_kernel(const int* __restrict__ ei, float* __restrict__ deg) {
  int e = blockIdx.x * 256 + threadIdx.x;
  if (e < EE) atomicAdd(&deg[ei[EE + e]], 1.0f);  // dst row
}

__global__ void dinv_kernel(const float* __restrict__ deg, float* __restrict__ dinv) {
  int n = blockIdx.x * 256 + threadIdx.x;
  if (n < NN) dinv[n] = 1.0f / sqrtf(deg[n]);  // deg >= 1 (self loop)
}

// xw[b,n,g] = sum_k h[b,n,k] * gcn_W[g,k]  ; 8 rows per block
__global__ __launch_bounds__(128) void xw_kernel(const float* __restrict__ h,
                                                 const float* __restrict__ gcn_WT,
                                                 float* __restrict__ xw) {
  const int r0 = blockIdx.x * 8;
  const int g = threadIdx.x;
  __shared__ float hs[8][HH];
  for (int m = 0; m < 8; ++m) hs[m][g] = h[(size_t)(r0 + m) * HH + g];
  __syncthreads();
  float acc[8] = {0, 0, 0, 0, 0, 0, 0, 0};
#pragma unroll 4
  for (int k = 0; k < HH; ++k) {
    float w = gcn_WT[k * HH + g];
#pragma unroll
    for (int m = 0; m < 8; ++m) acc[m] += hs[m][k] * w;
  }
  for (int m = 0; m < 8; ++m) xw[(size_t)(r0 + m) * HH + g] = acc[m];
}

// scatter: agg[b,dst,:] += xw[b,src,:] * norm(e); thread = (edge, channel)
__global__ void scatter_kernel(const int* __restrict__ ei, const float* __restrict__ xw,
                               const float* __restrict__ dinv, float* __restrict__ agg) {
  int gid = blockIdx.x * 256 + threadIdx.x;
  int e = gid >> 7;
  int jj = gid & 127;
  if (e >= EE) return;
  int s = ei[e];
  int d = ei[EE + e];
  float nrm = dinv[s] * dinv[d];
#pragma unroll
  for (int b = 0; b < NB; ++b) {
    float v = xw[((size_t)b * NN + s) * HH + jj] * nrm;
    atomicAdd(&agg[((size_t)b * NN + d) * HH + jj], v);
  }
}

// final: add self-loop + bias, relu, two dot heads. one wave per row.
__global__ __launch_bounds__(256) void final_kernel(
    const float* __restrict__ agg, const float* __restrict__ xw, const float* __restrict__ dinv,
    const float* __restrict__ gcn_b, const float* __restrict__ fcw_c, const float* __restrict__ fcb_c,
    const float* __restrict__ fcw_i, const float* __restrict__ fcb_i, float* __restrict__ out) {
  int row = blockIdx.x * 4 + (threadIdx.x >> 6);
  int lane = threadIdx.x & 63;
  int n = row % NN;
  float sn = dinv[n] * dinv[n];
  float sc = 0.0f, si = 0.0f;
  for (int jj = lane; jj < HH; jj += 64) {
    float v = agg[(size_t)row * HH + jj] + xw[(size_t)row * HH + jj] * sn + gcn_b[jj];
    v = fmaxf(v, 0.0f);
    sc += v * fcw_c[jj];
    si += v * fcw_i[jj];
  }
#pragma unroll
  for (int off = 32; off > 0; off >>= 1) {
    sc += __shfl_down(sc, off);
    si += __shfl_down(si, off);
  }
  if (lane == 0) {
    out[row] = sc + fcb_c[0];
    out[NB * NN + row] = si + fcb_i[0];
  }
}

extern "C" void kernel_launch(void* const* d_in, const int* in_sizes, int n_in,
                              void* d_out, int out_size, void* d_ws, size_t ws_size,
                              hipStream_t stream) {
  const float* x     = (const float*)d_in[0];
  const int*   ei    = (const int*)d_in[1];
  const float* W_ih  = (const float*)d_in[2];
  const float* W_hh  = (const float*)d_in[3];
  const float* b_ih  = (const float*)d_in[4];
  const float* b_hh  = (const float*)d_in[5];
  const float* gcn_W = (const float*)d_in[6];
  const float* gcn_b = (const float*)d_in[7];
  const float* fcw_c = (const float*)d_in[8];
  const float* fcb_c = (const float*)d_in[9];
  const float* fcw_i = (const float*)d_in[10];
  const float* fcb_i = (const float*)d_in[11];
  float* out = (float*)d_out;

  char* cur = (char*)d_ws;
  unsigned short* Wbh_hi = (unsigned short*)cur; cur += 65536 * 2;
  unsigned short* Wbh_lo = (unsigned short*)cur; cur += 65536 * 2;
  unsigned short* Wbi_hi = (unsigned short*)cur; cur += 16384 * 2;
  unsigned short* Wbi_lo = (unsigned short*)cur; cur += 16384 * 2;
  float* gcn_WT = (float*)cur; cur += 16384 * 4;
  float* bias   = (float*)cur; cur += 512 * 4;
  float* deg    = (float*)cur; cur += 4000 * 4;
  float* dinv   = (float*)cur; cur += 4000 * 4;
  float* h_all  = (float*)cur; cur += (size_t)4096000 * 4;
  // overlay region: xpk (98.3 MB, live only during lstm) | xw+agg (live after lstm)
  unsigned short* xpk = (unsigned short*)cur;           // 2000*24*2*512 ushorts
  float* xw  = (float*)cur;                              // 4,096,000 floats
  float* agg = xw + 4096000;                             // 4,096,000 floats

  setup_kernel<<<402, 256, 0, stream>>>(W_ih, W_hh, b_ih, b_hh, gcn_W,
                                        Wbh_hi, Wbh_lo, Wbi_hi, Wbi_lo,
                                        gcn_WT, bias, deg);
  xsplit_kernel<<<(2000 * TT * 64) / 256, 256, 0, stream>>>(x, xpk);
  lstm_kernel<<<(NB * NN) / 64, 512, 0, stream>>>(xpk, Wbh_hi, Wbh_lo, Wbi_hi, Wbi_lo,
                                                  bias, h_all);
  // xpk dead from here; agg/xw reuse its space
  hipMemsetAsync(agg, 0, (size_t)4096000 * sizeof(float), stream);
  deg_kernel<<<EE / 256, 256, 0, stream>>>(ei, deg);
  dinv_kernel<<<(NN + 255) / 256, 256, 0, stream>>>(deg, dinv);
  xw_kernel<<<(NB * NN) / 8, 128, 0, stream>>>(h_all, gcn_WT, xw);
  scatter_kernel<<<(EE * 128) / 256, 256, 0, stream>>>(ei, xw, dinv, agg);
  final_kernel<<<(NB * NN) / 4, 256, 0, stream>>>(agg, xw, dinv, gcn_b, fcw_c, fcb_c,
                                                  fcw_i, fcb_i, out);
}

// Round 11
// 1325.123 us; speedup vs baseline: 1.0010x; 1.0004x over previous
//
#include <hip/hip_runtime.h>

#define NB 8
#define TT 24
#define NN 4000
#define FF 32
#define HH 128
#define EE 64000

typedef float f32x4 __attribute__((ext_vector_type(4)));
typedef short bf16x8 __attribute__((ext_vector_type(8)));
#define MFMA16(a, b, c) __builtin_amdgcn_mfma_f32_16x16x32_bf16(a, b, c, 0, 0, 0)

// fast gate math: v_exp + v_rcp (rel err ~1e-7, negligible vs bf16-split error)
__device__ __forceinline__ float fsig(float x) {
  return __builtin_amdgcn_rcpf(1.0f + __expf(-x));
}
__device__ __forceinline__ float ftanh(float x) {
  return 1.0f - 2.0f * __builtin_amdgcn_rcpf(__expf(2.0f * x) + 1.0f);
}

// round-to-nearest-even fp32 -> bf16; returns bits, sets *hif to the bf16 value as fp32
__device__ __forceinline__ unsigned short rne16(float x, float* hif) {
  unsigned u = __float_as_uint(x);
  unsigned r = (u + 0x7FFFu + ((u >> 16) & 1u)) >> 16;
  *hif = __uint_as_float(r << 16);
  return (unsigned short)r;
}

// RNE-rounded bf16 in the TOP 16 bits (for perm-based pair packing)
__device__ __forceinline__ unsigned rnd_top(float x) {
  unsigned u = __float_as_uint(x);
  return u + 0x7FFFu + ((u >> 16) & 1u);
}

// ---------- setup: pack weights into MFMA fragment order (hi/lo split), combine bias, init deg ----------
__global__ void setup_kernel(const float* __restrict__ W_ih, const float* __restrict__ W_hh,
                             const float* __restrict__ b_ih, const float* __restrict__ b_hh,
                             const float* __restrict__ gcn_W,
                             unsigned short* __restrict__ Wbh_hi, unsigned short* __restrict__ Wbh_lo,
                             unsigned short* __restrict__ Wbi_hi, unsigned short* __restrict__ Wbi_lo,
                             float* __restrict__ gcn_WT, float* __restrict__ bias,
                             float* __restrict__ deg) {
  int idx = blockIdx.x * 256 + threadIdx.x;
  if (idx < 65536) {
    int e = idx & 7, l = (idx >> 3) & 63, ks = (idx >> 9) & 3, nt = idx >> 11;
    int gate = nt * 16 + (l & 15);
    int k = ks * 32 + (l >> 4) * 8 + e;
    float wv = W_hh[gate * 128 + k];
    float hif, d;
    unsigned short hb = rne16(wv, &hif);
    unsigned short lb = rne16(wv - hif, &d);
    Wbh_hi[idx] = hb;
    Wbh_lo[idx] = lb;
  } else if (idx < 65536 + 16384) {
    int p = idx - 65536;
    int e = p & 7, l = (p >> 3) & 63, nt = p >> 9;
    int gate = nt * 16 + (l & 15);
    int k = (l >> 4) * 8 + e;
    float wv = W_ih[gate * 32 + k];
    float hif, d;
    unsigned short hb = rne16(wv, &hif);
    unsigned short lb = rne16(wv - hif, &d);
    Wbi_hi[p] = hb;
    Wbi_lo[p] = lb;
  } else if (idx < 65536 + 16384 + 16384) {
    int p = idx - 65536 - 16384;
    int g = p & 127, k = p >> 7;
    gcn_WT[p] = gcn_W[g * 128 + k];
  } else if (idx < 65536 + 16384 + 16384 + 512) {
    int g = idx - (65536 + 16384 + 16384);
    bias[g] = b_ih[g] + b_hh[g];
  } else if (idx < 65536 + 16384 + 16384 + 512 + NN) {
    int n = idx - (65536 + 16384 + 16384 + 512);
    deg[n] = 1.0f;  // self-loop
  }
}

// ---------- x pre-split: B-fragment-ready bf16 hi/lo ----------
__global__ __launch_bounds__(256) void xsplit_kernel(const float* __restrict__ x,
                                                     unsigned short* __restrict__ xpk) {
  int gid = blockIdx.x * 256 + threadIdx.x;  // exactly 2000*24*64
  int l = gid & 63;
  int t = (gid >> 6) % TT;
  int rt = gid / (TT * 64);
  int col = l & 15, kc = l >> 4;
  int r = rt * 16 + col;              // NN%16==0 -> tile never straddles batch
  int b = (rt * 16) / NN;
  int n = r - b * NN;
  const float* src = x + (((size_t)b * TT + t) * NN + n) * FF + kc * 8;
  float4 p0 = *(const float4*)src;
  float4 p1 = *(const float4*)(src + 4);
  float xf[8] = {p0.x, p0.y, p0.z, p0.w, p1.x, p1.y, p1.z, p1.w};
  bf16x8 vh, vl;
#pragma unroll
  for (int e = 0; e < 8; ++e) {
    float hif, d;
    vh[e] = (short)rne16(xf[e], &hif);
    vl[e] = (short)rne16(xf[e] - hif, &d);
  }
  size_t ob = (size_t)(rt * TT + t) * 1024 + l * 8;
  *(bf16x8*)(xpk + ob) = vh;
  *(bf16x8*)(xpk + ob + 512) = vl;
}

// ---------- LSTM via split-bf16 MFMA, anti-phase groups ----------
// 8 waves, 64 seqs/block = 2 groups of 32 seqs (waves 0-3 = A, 4-7 = B). Group B runs one
// barrier-interval behind A; SIMD s hosts waves s (A) and s+4 (B), so every interval pairs
// {one wave's MFMA phase} || {the other's gate epilogue}.
// __launch_bounds__(512, 1): 1 BLOCK/CU (2nd arg = min blocks/CU on this toolchain, verified
// r5/r9: (512,4)->64 VGPR, (512,2)->128 VGPR) => 2 waves/SIMD => 256-VGPR class, no spill.
__global__ __launch_bounds__(512, 1) void lstm_kernel(
    const unsigned short* __restrict__ xpk,  // pre-split x fragments
    const unsigned short* __restrict__ Wbh_hi, const unsigned short* __restrict__ Wbh_lo,
    const unsigned short* __restrict__ Wbi_hi, const unsigned short* __restrict__ Wbi_lo,
    const float* __restrict__ bias,          // [512] combined
    float* __restrict__ h_out)               // [B*N, H] fp32
{
  __shared__ unsigned short hbuf[2][2][32 * 128];  // [grp][hi/lo][row*128+j] : 32 KB
  const int tid = threadIdx.x;
  const int w = tid >> 6, l = tid & 63;
  const int grp = w >> 2, w4 = w & 3;
  const int col = l & 15, kc = l >> 4;
  const int blk = blockIdx.x;

  // zero both groups' h(0)
  {
    uint4* p0 = (uint4*)&hbuf[0][0][0];
    for (int i = tid; i < 2048; i += 512) p0[i] = make_uint4(0, 0, 0, 0);
  }

  const char* hb_hi = (const char*)&hbuf[grp][0][0];
  const char* hb_lo = (const char*)&hbuf[grp][1][0];
  char* hw_hi = (char*)&hbuf[grp][0][0];
  char* hw_lo = (char*)&hbuf[grp][1][0];

  // bias fragments: bqq[q] = bias[(4q+w4)*16 + 4kc ..+4) (C-operand seed at ks==0)
  f32x4 bqq[8];
#pragma unroll
  for (int q = 0; q < 8; ++q) bqq[q] = *(const f32x4*)(bias + (4 * q + w4) * 16 + 4 * kc);

  float c[2][2][4];  // [sq][u][r]
#pragma unroll
  for (int sq = 0; sq < 2; ++sq)
#pragma unroll
    for (int u = 0; u < 2; ++u)
#pragma unroll
      for (int r = 0; r < 4; ++r) c[sq][u][r] = 0.0f;

  const int rtA = blk * 4 + grp * 2;  // global 16-row tile base for this group

  __syncthreads();              // h(0) visible
  if (grp) __syncthreads();     // offset group B by one interval (counting barrier pairing)

  for (int t = 0; t < TT; ++t) {
    // ================= MFMA phase =================
    // x fragments (pre-split) — issue first, consumed last
    bf16x8 xh[2], xl[2];
#pragma unroll
    for (int sq = 0; sq < 2; ++sq) {
      const unsigned short* xb = xpk + ((size_t)(rtA + sq) * TT + t) * 1024 + l * 8;
      xh[sq] = *(const bf16x8*)xb;
      xl[sq] = *(const bf16x8*)(xb + 512);
    }

    f32x4 acc[2][8];  // [sq][q] — inside loop body, static indices only
    __builtin_amdgcn_s_setprio(1);
    // recurrence: W_hh(A) x h(B), split-bf16
#pragma unroll
    for (int ks = 0; ks < 4; ++ks) {
      bf16x8 bh[2], bl_[2];
#pragma unroll
      for (int sq = 0; sq < 2; ++sq) {
        int off = (16 * sq + col) * 256 + (((4 * ks + kc) ^ col) << 4);
        bh[sq] = *(const bf16x8*)(hb_hi + off);
        bl_[sq] = *(const bf16x8*)(hb_lo + off);
      }
#pragma unroll
      for (int q = 0; q < 8; ++q) {
        size_t wo = ((size_t)((4 * q + w4) * 4 + ks) * 64 + l) * 8;
        bf16x8 wh = *(const bf16x8*)(Wbh_hi + wo);
        bf16x8 wl = *(const bf16x8*)(Wbh_lo + wo);
#pragma unroll
        for (int sq = 0; sq < 2; ++sq) {
          acc[sq][q] = MFMA16(wh, bh[sq], ks == 0 ? bqq[q] : acc[sq][q]);
          acc[sq][q] = MFMA16(wh, bl_[sq], acc[sq][q]);
          acc[sq][q] = MFMA16(wl, bh[sq], acc[sq][q]);
        }
      }
    }
    // input projection: W_ih(A) x x(B)
#pragma unroll
    for (int q = 0; q < 8; ++q) {
      size_t wo = ((size_t)(4 * q + w4) * 64 + l) * 8;
      bf16x8 wh = *(const bf16x8*)(Wbi_hi + wo);
      bf16x8 wl = *(const bf16x8*)(Wbi_lo + wo);
#pragma unroll
      for (int sq = 0; sq < 2; ++sq) {
        acc[sq][q] = MFMA16(wh, xh[sq], acc[sq][q]);
        acc[sq][q] = MFMA16(wh, xl[sq], acc[sq][q]);
        acc[sq][q] = MFMA16(wl, xh[sq], acc[sq][q]);
      }
    }
    __builtin_amdgcn_s_setprio(0);

    __syncthreads();

    // ================= epilogue phase =================
    // q = 2g+u : gate g of j-block jb = w4 + 4u
#pragma unroll
    for (int sq = 0; sq < 2; ++sq) {
#pragma unroll
      for (int u = 0; u < 2; ++u) {
        int jb = w4 + 4 * u;
        unsigned uh[4], ul[4];
        float hv[4];
#pragma unroll
        for (int r = 0; r < 4; ++r) {
          float iv = fsig(acc[sq][0 + u][r]);
          float fv = fsig(acc[sq][2 + u][r]);
          float gv = ftanh(acc[sq][4 + u][r]);
          float ov = fsig(acc[sq][6 + u][r]);
          float cc = fv * c[sq][u][r] + iv * gv;
          c[sq][u][r] = cc;
          float hh = ov * ftanh(cc);
          hv[r] = hh;
          unsigned uu = __float_as_uint(hh);
          uh[r] = uu;  // hi = trunc bf16 (bytes 2,3)
          float hif = __uint_as_float(uu & 0xFFFF0000u);
          ul[r] = rnd_top(hh - hif);  // lo = RNE bf16 in top bits
        }
        // pack pairs via byte-perm: dst = [lo16(p0), hi16<-p1]
        uint2 phi, plo;
        phi.x = __builtin_amdgcn_perm(uh[1], uh[0], 0x07060302u);
        phi.y = __builtin_amdgcn_perm(uh[3], uh[2], 0x07060302u);
        plo.x = __builtin_amdgcn_perm(ul[1], ul[0], 0x07060302u);
        plo.y = __builtin_amdgcn_perm(ul[3], ul[2], 0x07060302u);
        int row = 16 * sq + col;
        int cs = (2 * jb + (kc >> 1)) ^ col;
        int woff = row * 256 + cs * 16 + 8 * (kc & 1);
        *(uint2*)(hw_hi + woff) = phi;
        *(uint2*)(hw_lo + woff) = plo;
        if (t == TT - 1) {
          int rowg = blk * 64 + grp * 32 + 16 * sq + col;
          *(float4*)&h_out[(size_t)rowg * HH + 16 * jb + 4 * kc] =
              make_float4(hv[0], hv[1], hv[2], hv[3]);
        }
      }
    }
    __syncthreads();
  }
  if (!grp) __syncthreads();    // rebalance barrier count
}

// ---------- GCN ----------
__global__ void deg_kernel(const int* __restrict__ ei, float* __restrict__ deg) {
  int e = blockIdx.x * 256 + threadIdx.x;
  if (e < EE) atomicAdd(&deg[ei[EE + e]], 1.0f);  // dst row
}

__global__ void dinv_kernel(const float* __restrict__ deg, float* __restrict__ dinv) {
  int n = blockIdx.x * 256 + threadIdx.x;
  if (n < NN) dinv[n] = 1.0f / sqrtf(deg[n]);  // deg >= 1 (self loop)
}

// xw[b,n,g] = sum_k h[b,n,k] * gcn_W[g,k]  ; 8 rows per block
__global__ __launch_bounds__(128) void xw_kernel(const float* __restrict__ h,
                                                 const float* __restrict__ gcn_WT,
                                                 float* __restrict__ xw) {
  const int r0 = blockIdx.x * 8;
  const int g = threadIdx.x;
  __shared__ float hs[8][HH];
  for (int m = 0; m < 8; ++m) hs[m][g] = h[(size_t)(r0 + m) * HH + g];
  __syncthreads();
  float acc[8] = {0, 0, 0, 0, 0, 0, 0, 0};
#pragma unroll 4
  for (int k = 0; k < HH; ++k) {
    float w = gcn_WT[k * HH + g];
#pragma unroll
    for (int m = 0; m < 8; ++m) acc[m] += hs[m][k] * w;
  }
  for (int m = 0; m < 8; ++m) xw[(size_t)(r0 + m) * HH + g] = acc[m];
}

// scatter: agg[b,dst,:] += xw[b,src,:] * norm(e); thread = (edge, channel)
__global__ void scatter_kernel(const int* __restrict__ ei, const float* __restrict__ xw,
                               const float* __restrict__ dinv, float* __restrict__ agg) {
  int gid = blockIdx.x * 256 + threadIdx.x;
  int e = gid >> 7;
  int jj = gid & 127;
  if (e >= EE) return;
  int s = ei[e];
  int d = ei[EE + e];
  float nrm = dinv[s] * dinv[d];
#pragma unroll
  for (int b = 0; b < NB; ++b) {
    float v = xw[((size_t)b * NN + s) * HH + jj] * nrm;
    atomicAdd(&agg[((size_t)b * NN + d) * HH + jj], v);
  }
}

// final: add self-loop + bias, relu, two dot heads. one wave per row.
__global__ __launch_bounds__(256) void final_kernel(
    const float* __restrict__ agg, const float* __restrict__ xw, const float* __restrict__ dinv,
    const float* __restrict__ gcn_b, const float* __restrict__ fcw_c, const float* __restrict__ fcb_c,
    const float* __restrict__ fcw_i, const float* __restrict__ fcb_i, float* __restrict__ out) {
  int row = blockIdx.x * 4 + (threadIdx.x >> 6);
  int lane = threadIdx.x & 63;
  int n = row % NN;
  float sn = dinv[n] * dinv[n];
  float sc = 0.0f, si = 0.0f;
  for (int jj = lane; jj < HH; jj += 64) {
    float v = agg[(size_t)row * HH + jj] + xw[(size_t)row * HH + jj] * sn + gcn_b[jj];
    v = fmaxf(v, 0.0f);
    sc += v * fcw_c[jj];
    si += v * fcw_i[jj];
  }
#pragma unroll
  for (int off = 32; off > 0; off >>= 1) {
    sc += __shfl_down(sc, off);
    si += __shfl_down(si, off);
  }
  if (lane == 0) {
    out[row] = sc + fcb_c[0];
    out[NB * NN + row] = si + fcb_i[0];
  }
}

extern "C" void kernel_launch(void* const* d_in, const int* in_sizes, int n_in,
                              void* d_out, int out_size, void* d_ws, size_t ws_size,
                              hipStream_t stream) {
  const float* x     = (const float*)d_in[0];
  const int*   ei    = (const int*)d_in[1];
  const float* W_ih  = (const float*)d_in[2];
  const float* W_hh  = (const float*)d_in[3];
  const float* b_ih  = (const float*)d_in[4];
  const float* b_hh  = (const float*)d_in[5];
  const float* gcn_W = (const float*)d_in[6];
  const float* gcn_b = (const float*)d_in[7];
  const float* fcw_c = (const float*)d_in[8];
  const float* fcb_c = (const float*)d_in[9];
  const float* fcw_i = (const float*)d_in[10];
  const float* fcb_i = (const float*)d_in[11];
  float* out = (float*)d_out;

  char* cur = (char*)d_ws;
  unsigned short* Wbh_hi = (unsigned short*)cur; cur += 65536 * 2;
  unsigned short* Wbh_lo = (unsigned short*)cur; cur += 65536 * 2;
  unsigned short* Wbi_hi = (unsigned short*)cur; cur += 16384 * 2;
  unsigned short* Wbi_lo = (unsigned short*)cur; cur += 16384 * 2;
  float* gcn_WT = (float*)cur; cur += 16384 * 4;
  float* bias   = (float*)cur; cur += 512 * 4;
  float* deg    = (float*)cur; cur += 4000 * 4;
  float* dinv   = (float*)cur; cur += 4000 * 4;
  float* h_all  = (float*)cur; cur += (size_t)4096000 * 4;
  // overlay region: xpk (98.3 MB, live only during lstm) | xw+agg (live after lstm)
  unsigned short* xpk = (unsigned short*)cur;           // 2000*24*2*512 ushorts
  float* xw  = (float*)cur;                              // 4,096,000 floats
  float* agg = xw + 4096000;                             // 4,096,000 floats

  setup_kernel<<<402, 256, 0, stream>>>(W_ih, W_hh, b_ih, b_hh, gcn_W,
                                        Wbh_hi, Wbh_lo, Wbi_hi, Wbi_lo,
                                        gcn_WT, bias, deg);
  xsplit_kernel<<<(2000 * TT * 64) / 256, 256, 0, stream>>>(x, xpk);
  lstm_kernel<<<(NB * NN) / 64, 512, 0, stream>>>(xpk, Wbh_hi, Wbh_lo, Wbi_hi, Wbi_lo,
                                                  bias, h_all);
  // xpk dead from here; agg/xw reuse its space
  hipMemsetAsync(agg, 0, (size_t)4096000 * sizeof(float), stream);
  deg_kernel<<<EE / 256, 256, 0, stream>>>(ei, deg);
  dinv_kernel<<<(NN + 255) / 256, 256, 0, stream>>>(deg, dinv);
  xw_kernel<<<(NB * NN) / 8, 128, 0, stream>>>(h_all, gcn_WT, xw);
  scatter_kernel<<<(EE * 128) / 256, 256, 0, stream>>>(ei, xw, dinv, agg);
  final_kernel<<<(NB * NN) / 4, 256, 0, stream>>>(agg, xw, dinv, gcn_b, fcw_c, fcb_c,
                                                  fcw_i, fcb_i, out);
}

// Round 12
// 482.540 us; speedup vs baseline: 2.7488x; 2.7461x over previous
//
#include <hip/hip_runtime.h>

#define NB 8
#define TT 24
#define NN 4000
#define FF 32
#define HH 128
#define EE 64000

typedef float f32x4 __attribute__((ext_vector_type(4)));
typedef short bf16x8 __attribute__((ext_vector_type(8)));
#define MFMA16(a, b, c) __builtin_amdgcn_mfma_f32_16x16x32_bf16(a, b, c, 0, 0, 0)

__device__ __forceinline__ float fsig(float x) {
  return __builtin_amdgcn_rcpf(1.0f + __expf(-x));
}
__device__ __forceinline__ float ftanh(float x) {
  return 1.0f - 2.0f * __builtin_amdgcn_rcpf(__expf(2.0f * x) + 1.0f);
}

__device__ __forceinline__ unsigned short rne16(float x, float* hif) {
  unsigned u = __float_as_uint(x);
  unsigned r = (u + 0x7FFFu + ((u >> 16) & 1u)) >> 16;
  *hif = __uint_as_float(r << 16);
  return (unsigned short)r;
}

__device__ __forceinline__ unsigned rnd_top(float x) {
  unsigned u = __float_as_uint(x);
  return u + 0x7FFFu + ((u >> 16) & 1u);
}

// ---------- setup: pack weights (hi/lo split, MFMA frag order), bias, deg=1, ecnt=0, fillc=0 ----------
__global__ void setup_kernel(const float* __restrict__ W_ih, const float* __restrict__ W_hh,
                             const float* __restrict__ b_ih, const float* __restrict__ b_hh,
                             const float* __restrict__ gcn_W,
                             unsigned short* __restrict__ Wbh_hi, unsigned short* __restrict__ Wbh_lo,
                             unsigned short* __restrict__ Wbi_hi, unsigned short* __restrict__ Wbi_lo,
                             float* __restrict__ gcn_WT, float* __restrict__ bias,
                             float* __restrict__ deg, int* __restrict__ ecnt, int* __restrict__ fillc) {
  int idx = blockIdx.x * 256 + threadIdx.x;
  if (idx < 65536) {
    int e = idx & 7, l = (idx >> 3) & 63, ks = (idx >> 9) & 3, nt = idx >> 11;
    int gate = nt * 16 + (l & 15);
    int k = ks * 32 + (l >> 4) * 8 + e;
    float wv = W_hh[gate * 128 + k];
    float hif, d;
    unsigned short hb = rne16(wv, &hif);
    unsigned short lb = rne16(wv - hif, &d);
    Wbh_hi[idx] = hb;
    Wbh_lo[idx] = lb;
  } else if (idx < 65536 + 16384) {
    int p = idx - 65536;
    int e = p & 7, l = (p >> 3) & 63, nt = p >> 9;
    int gate = nt * 16 + (l & 15);
    int k = (l >> 4) * 8 + e;
    float wv = W_ih[gate * 32 + k];
    float hif, d;
    unsigned short hb = rne16(wv, &hif);
    unsigned short lb = rne16(wv - hif, &d);
    Wbi_hi[p] = hb;
    Wbi_lo[p] = lb;
  } else if (idx < 65536 + 16384 + 16384) {
    int p = idx - 65536 - 16384;
    int g = p & 127, k = p >> 7;
    gcn_WT[p] = gcn_W[g * 128 + k];
  } else if (idx < 65536 + 16384 + 16384 + 512) {
    int g = idx - (65536 + 16384 + 16384);
    bias[g] = b_ih[g] + b_hh[g];
  } else if (idx < 65536 + 16384 + 16384 + 512 + NN) {
    int n = idx - (65536 + 16384 + 16384 + 512);
    deg[n] = 1.0f;  // self-loop
  } else if (idx < 65536 + 16384 + 16384 + 512 + 2 * NN) {
    int n = idx - (65536 + 16384 + 16384 + 512 + NN);
    ecnt[n] = 0;
  } else if (idx < 65536 + 16384 + 16384 + 512 + 3 * NN) {
    int n = idx - (65536 + 16384 + 16384 + 512 + 2 * NN);
    fillc[n] = 0;
  }
}

// ---------- x pre-split: B-fragment-ready bf16 hi/lo ----------
__global__ __launch_bounds__(256) void xsplit_kernel(const float* __restrict__ x,
                                                     unsigned short* __restrict__ xpk) {
  int gid = blockIdx.x * 256 + threadIdx.x;  // exactly 2000*24*64
  int l = gid & 63;
  int t = (gid >> 6) % TT;
  int rt = gid / (TT * 64);
  int col = l & 15, kc = l >> 4;
  int r = rt * 16 + col;  // NN%16==0 -> tile never straddles batch
  int b = (rt * 16) / NN;
  int n = r - b * NN;
  const float* src = x + (((size_t)b * TT + t) * NN + n) * FF + kc * 8;
  float4 p0 = *(const float4*)src;
  float4 p1 = *(const float4*)(src + 4);
  float xf[8] = {p0.x, p0.y, p0.z, p0.w, p1.x, p1.y, p1.z, p1.w};
  bf16x8 vh, vl;
#pragma unroll
  for (int e = 0; e < 8; ++e) {
    float hif, d;
    vh[e] = (short)rne16(xf[e], &hif);
    vl[e] = (short)rne16(xf[e] - hif, &d);
  }
  size_t ob = (size_t)(rt * TT + t) * 1024 + l * 8;
  *(bf16x8*)(xpk + ob) = vh;
  *(bf16x8*)(xpk + ob + 512) = vl;
}

// ---------- LSTM via split-bf16 MFMA: 4 waves, 32 seqs/block, 1000 blocks ----------
// Small blocks so 4 can co-reside per CU (4 waves/SIMD) -> independent blocks overlap
// MFMA phase with gate epilogue naturally. Single-phase r7-proven code shape:
// acc in-loop, no state across barriers except c[] and pointers.
// Wave w (0..3) owns n-tiles nt = 4q+w (q=0..7). Lane (col,kc): seqs {16sq+col},
// j-cols j0 = 16(w+4u)+4kc for u in {0,1}. q = 2g+u maps gate g, j-block jb=w+4u.
__global__ __launch_bounds__(256) void lstm_kernel(
    const unsigned short* __restrict__ xpk,
    const unsigned short* __restrict__ Wbh_hi, const unsigned short* __restrict__ Wbh_lo,
    const unsigned short* __restrict__ Wbi_hi, const unsigned short* __restrict__ Wbi_lo,
    const float* __restrict__ bias,
    float* __restrict__ h_out) {
  __shared__ unsigned short hbuf[2][2][32 * 128];  // [buf][hi/lo][row*128+j] : 32 KB
  const int tid = threadIdx.x;
  const int w = tid >> 6, l = tid & 63;
  const int col = l & 15, kc = l >> 4;
  const int blk = blockIdx.x;

  {
    uint4* p0 = (uint4*)&hbuf[0][0][0];
    for (int i = tid; i < 1024; i += 256) p0[i] = make_uint4(0, 0, 0, 0);
  }

  float c[2][2][4];  // [sq][u][r]
#pragma unroll
  for (int sq = 0; sq < 2; ++sq)
#pragma unroll
    for (int u = 0; u < 2; ++u)
#pragma unroll
      for (int r = 0; r < 4; ++r) c[sq][u][r] = 0.0f;

  __syncthreads();

  for (int t = 0; t < TT; ++t) {
    const char* hr_hi = (const char*)&hbuf[t & 1][0][0];
    const char* hr_lo = (const char*)&hbuf[t & 1][1][0];
    char* hw_hi = (char*)&hbuf[(t + 1) & 1][0][0];
    char* hw_lo = (char*)&hbuf[(t + 1) & 1][1][0];

    // x fragments (pre-split) — issue first
    bf16x8 xh[2], xl[2];
#pragma unroll
    for (int sq = 0; sq < 2; ++sq) {
      const unsigned short* xb = xpk + ((size_t)(blk * 2 + sq) * TT + t) * 1024 + l * 8;
      xh[sq] = *(const bf16x8*)xb;
      xl[sq] = *(const bf16x8*)(xb + 512);
    }

    f32x4 acc[2][8];  // [sq][q] — in-loop, static indices
#pragma unroll
    for (int sq = 0; sq < 2; ++sq)
#pragma unroll
      for (int q = 0; q < 8; ++q) acc[sq][q] = (f32x4){0.f, 0.f, 0.f, 0.f};

    __builtin_amdgcn_s_setprio(1);
    // recurrence: W_hh(A) x h(B), split-bf16 (3 MFMA per tile-pair)
#pragma unroll
    for (int ks = 0; ks < 4; ++ks) {
      bf16x8 bh[2], bl_[2];
#pragma unroll
      for (int sq = 0; sq < 2; ++sq) {
        int off = (16 * sq + col) * 256 + (((4 * ks + kc) ^ col) << 4);
        bh[sq] = *(const bf16x8*)(hr_hi + off);
        bl_[sq] = *(const bf16x8*)(hr_lo + off);
      }
#pragma unroll
      for (int q = 0; q < 8; ++q) {
        size_t wo = ((size_t)((4 * q + w) * 4 + ks) * 64 + l) * 8;
        bf16x8 wh = *(const bf16x8*)(Wbh_hi + wo);
        bf16x8 wl = *(const bf16x8*)(Wbh_lo + wo);
#pragma unroll
        for (int sq = 0; sq < 2; ++sq) {
          acc[sq][q] = MFMA16(wh, bh[sq], acc[sq][q]);
          acc[sq][q] = MFMA16(wh, bl_[sq], acc[sq][q]);
          acc[sq][q] = MFMA16(wl, bh[sq], acc[sq][q]);
        }
      }
    }
    // input projection: W_ih(A) x x(B)
#pragma unroll
    for (int q = 0; q < 8; ++q) {
      size_t wo = ((size_t)(4 * q + w) * 64 + l) * 8;
      bf16x8 wh = *(const bf16x8*)(Wbi_hi + wo);
      bf16x8 wl = *(const bf16x8*)(Wbi_lo + wo);
#pragma unroll
      for (int sq = 0; sq < 2; ++sq) {
        acc[sq][q] = MFMA16(wh, xh[sq], acc[sq][q]);
        acc[sq][q] = MFMA16(wh, xl[sq], acc[sq][q]);
        acc[sq][q] = MFMA16(wl, xh[sq], acc[sq][q]);
      }
    }
    __builtin_amdgcn_s_setprio(0);

    // epilogue: gates (i,f,g,o), state update, swizzled b64 LDS writes
#pragma unroll
    for (int u = 0; u < 2; ++u) {
      int jb = w + 4 * u;
      f32x4 bi4 = *(const f32x4*)(bias + 0 * 128 + jb * 16 + 4 * kc);
      f32x4 bf4 = *(const f32x4*)(bias + 1 * 128 + jb * 16 + 4 * kc);
      f32x4 bg4 = *(const f32x4*)(bias + 2 * 128 + jb * 16 + 4 * kc);
      f32x4 bo4 = *(const f32x4*)(bias + 3 * 128 + jb * 16 + 4 * kc);
#pragma unroll
      for (int sq = 0; sq < 2; ++sq) {
        unsigned uh[4], ul[4];
        float hv[4];
#pragma unroll
        for (int r = 0; r < 4; ++r) {
          float iv = fsig(acc[sq][0 + u][r] + bi4[r]);
          float fv = fsig(acc[sq][2 + u][r] + bf4[r]);
          float gv = ftanh(acc[sq][4 + u][r] + bg4[r]);
          float ov = fsig(acc[sq][6 + u][r] + bo4[r]);
          float cc = fv * c[sq][u][r] + iv * gv;
          c[sq][u][r] = cc;
          float hh = ov * ftanh(cc);
          hv[r] = hh;
          unsigned uu = __float_as_uint(hh);
          uh[r] = uu;  // hi = trunc bf16 (bytes 2,3)
          float hif = __uint_as_float(uu & 0xFFFF0000u);
          ul[r] = rnd_top(hh - hif);  // lo = RNE bf16 in top bits
        }
        uint2 phi, plo;
        phi.x = __builtin_amdgcn_perm(uh[1], uh[0], 0x07060302u);
        phi.y = __builtin_amdgcn_perm(uh[3], uh[2], 0x07060302u);
        plo.x = __builtin_amdgcn_perm(ul[1], ul[0], 0x07060302u);
        plo.y = __builtin_amdgcn_perm(ul[3], ul[2], 0x07060302u);
        int row = 16 * sq + col;
        int cs = (2 * jb + (kc >> 1)) ^ col;
        int woff = row * 256 + cs * 16 + 8 * (kc & 1);
        *(uint2*)(hw_hi + woff) = phi;
        *(uint2*)(hw_lo + woff) = plo;
        if (t == TT - 1) {
          int rowg = blk * 32 + 16 * sq + col;
          *(float4*)&h_out[(size_t)rowg * HH + 16 * jb + 4 * kc] =
              make_float4(hv[0], hv[1], hv[2], hv[3]);
        }
      }
    }
    __syncthreads();
  }
}

// ---------- GCN: CSR build + gather (no atomics in hot path) ----------
__global__ void hist_kernel(const int* __restrict__ ei, float* __restrict__ deg,
                            int* __restrict__ ecnt) {
  int e = blockIdx.x * 256 + threadIdx.x;
  if (e < EE) {
    int d = ei[EE + e];
    atomicAdd(&deg[d], 1.0f);
    atomicAdd(&ecnt[d], 1);
  }
}

__global__ void dinv_kernel(const float* __restrict__ deg, float* __restrict__ dinv) {
  int n = blockIdx.x * 256 + threadIdx.x;
  if (n < NN) dinv[n] = 1.0f / sqrtf(deg[n]);  // deg >= 1 (self loop)
}

// single-block Hillis-Steele scan over 4096 (NN=4000 padded); rowptr[0..NN]
__global__ __launch_bounds__(1024) void scan_kernel(const int* __restrict__ ecnt,
                                                    int* __restrict__ rowptr) {
  __shared__ int s[4096];
  int tid = threadIdx.x;
  for (int i = tid; i < 4096; i += 1024) s[i] = (i < NN) ? ecnt[i] : 0;
  __syncthreads();
  for (int off = 1; off < 4096; off <<= 1) {
    int v[4];
#pragma unroll
    for (int k = 0; k < 4; ++k) {
      int i = tid + k * 1024;
      v[k] = s[i] + ((i >= off) ? s[i - off] : 0);
    }
    __syncthreads();
#pragma unroll
    for (int k = 0; k < 4; ++k) s[tid + k * 1024] = v[k];
    __syncthreads();
  }
  for (int i = tid; i <= NN; i += 1024) rowptr[i] = (i == 0) ? 0 : s[i - 1];
}

__global__ void fill_kernel(const int* __restrict__ ei, const float* __restrict__ dinv,
                            const int* __restrict__ rowptr, int* __restrict__ fillc,
                            int2* __restrict__ epk) {
  int e = blockIdx.x * 256 + threadIdx.x;
  if (e >= EE) return;
  int s = ei[e], d = ei[EE + e];
  int pos = rowptr[d] + atomicAdd(&fillc[d], 1);
  float nrm = dinv[s] * dinv[d];
  epk[pos] = make_int2(s, __float_as_int(nrm));
}

// xw[b,n,g] = sum_k h[b,n,k] * gcn_W[g,k]  ; 8 rows per block
__global__ __launch_bounds__(128) void xw_kernel(const float* __restrict__ h,
                                                 const float* __restrict__ gcn_WT,
                                                 float* __restrict__ xw) {
  const int r0 = blockIdx.x * 8;
  const int g = threadIdx.x;
  __shared__ float hs[8][HH];
  for (int m = 0; m < 8; ++m) hs[m][g] = h[(size_t)(r0 + m) * HH + g];
  __syncthreads();
  float acc[8] = {0, 0, 0, 0, 0, 0, 0, 0};
#pragma unroll 4
  for (int k = 0; k < HH; ++k) {
    float w = gcn_WT[k * HH + g];
#pragma unroll
    for (int m = 0; m < 8; ++m) acc[m] += hs[m][k] * w;
  }
  for (int m = 0; m < 8; ++m) xw[(size_t)(r0 + m) * HH + g] = acc[m];
}

// gather + self-loop + bias + relu + both heads, fused. 1 block = 1 dst node, 128 threads.
__global__ __launch_bounds__(128) void gather_final_kernel(
    const float* __restrict__ xw, const float* __restrict__ dinv,
    const int* __restrict__ rowptr, const int2* __restrict__ epk,
    const float* __restrict__ gcn_b,
    const float* __restrict__ fcw_c, const float* __restrict__ fcb_c,
    const float* __restrict__ fcw_i, const float* __restrict__ fcb_i,
    float* __restrict__ out) {
  const int d = blockIdx.x;
  const int j = threadIdx.x;
  float acc[NB];
#pragma unroll
  for (int b = 0; b < NB; ++b) acc[b] = 0.0f;
  const int p0 = rowptr[d], p1 = rowptr[d + 1];
  for (int p = p0; p < p1; ++p) {
    int2 ep = epk[p];
    int s = ep.x;
    float nrm = __int_as_float(ep.y);
#pragma unroll
    for (int b = 0; b < NB; ++b)
      acc[b] += xw[((size_t)b * NN + s) * HH + j] * nrm;
  }
  float sn = dinv[d] * dinv[d];
  float bj = gcn_b[j], wc = fcw_c[j], wi = fcw_i[j];
  __shared__ float red[2][NB][2];
  int lane = j & 63, wv = j >> 6;
#pragma unroll
  for (int b = 0; b < NB; ++b) {
    float v = acc[b] + xw[((size_t)b * NN + d) * HH + j] * sn + bj;
    v = fmaxf(v, 0.0f);
    float sc = v * wc, si = v * wi;
#pragma unroll
    for (int off = 32; off > 0; off >>= 1) {
      sc += __shfl_down(sc, off);
      si += __shfl_down(si, off);
    }
    if (lane == 0) {
      red[wv][b][0] = sc;
      red[wv][b][1] = si;
    }
  }
  __syncthreads();
  if (j < NB) {
    out[(size_t)j * NN + d] = red[0][j][0] + red[1][j][0] + fcb_c[0];
    out[(size_t)(NB + j) * NN + d] = red[0][j][1] + red[1][j][1] + fcb_i[0];
  }
}

extern "C" void kernel_launch(void* const* d_in, const int* in_sizes, int n_in,
                              void* d_out, int out_size, void* d_ws, size_t ws_size,
                              hipStream_t stream) {
  const float* x     = (const float*)d_in[0];
  const int*   ei    = (const int*)d_in[1];
  const float* W_ih  = (const float*)d_in[2];
  const float* W_hh  = (const float*)d_in[3];
  const float* b_ih  = (const float*)d_in[4];
  const float* b_hh  = (const float*)d_in[5];
  const float* gcn_W = (const float*)d_in[6];
  const float* gcn_b = (const float*)d_in[7];
  const float* fcw_c = (const float*)d_in[8];
  const float* fcb_c = (const float*)d_in[9];
  const float* fcw_i = (const float*)d_in[10];
  const float* fcb_i = (const float*)d_in[11];
  float* out = (float*)d_out;

  char* cur = (char*)d_ws;
  unsigned short* Wbh_hi = (unsigned short*)cur; cur += 65536 * 2;
  unsigned short* Wbh_lo = (unsigned short*)cur; cur += 65536 * 2;
  unsigned short* Wbi_hi = (unsigned short*)cur; cur += 16384 * 2;
  unsigned short* Wbi_lo = (unsigned short*)cur; cur += 16384 * 2;
  float* gcn_WT = (float*)cur; cur += 16384 * 4;
  float* bias   = (float*)cur; cur += 512 * 4;
  float* deg    = (float*)cur; cur += 4096 * 4;
  float* dinv   = (float*)cur; cur += 4096 * 4;
  int*   ecnt   = (int*)cur;   cur += 4096 * 4;
  int*   fillc  = (int*)cur;   cur += 4096 * 4;
  int*   rowptr = (int*)cur;   cur += 8192 * 4;
  int2*  epk    = (int2*)cur;  cur += (size_t)EE * 8;
  float* h_all  = (float*)cur; cur += (size_t)4096000 * 4;
  // overlay: xpk (98.3 MB, live only during lstm) | xw (live after lstm)
  unsigned short* xpk = (unsigned short*)cur;  // 2000*24*2*512 ushorts
  float* xw = (float*)cur;                     // 4,096,000 floats

  setup_kernel<<<433, 256, 0, stream>>>(W_ih, W_hh, b_ih, b_hh, gcn_W,
                                        Wbh_hi, Wbh_lo, Wbi_hi, Wbi_lo,
                                        gcn_WT, bias, deg, ecnt, fillc);
  xsplit_kernel<<<(2000 * TT * 64) / 256, 256, 0, stream>>>(x, xpk);
  lstm_kernel<<<(NB * NN) / 32, 256, 0, stream>>>(xpk, Wbh_hi, Wbh_lo, Wbi_hi, Wbi_lo,
                                                  bias, h_all);
  hist_kernel<<<EE / 256, 256, 0, stream>>>(ei, deg, ecnt);
  dinv_kernel<<<(NN + 255) / 256, 256, 0, stream>>>(deg, dinv);
  scan_kernel<<<1, 1024, 0, stream>>>(ecnt, rowptr);
  fill_kernel<<<EE / 256, 256, 0, stream>>>(ei, dinv, rowptr, fillc, epk);
  xw_kernel<<<(NB * NN) / 8, 128, 0, stream>>>(h_all, gcn_WT, xw);
  gather_final_kernel<<<NN, 128, 0, stream>>>(xw, dinv, rowptr, epk, gcn_b,
                                              fcw_c, fcb_c, fcw_i, fcb_i, out);
}